// Round 1
// baseline (12480.283 us; speedup 1.0000x reference)
//
#include <hip/hip_runtime.h>
#include <hip/hip_bf16.h>

// Problem: BATCH=128, SEQ=1024, DIN=512, HID=512 (all fp32)
// out = final hidden state (128, 512) of h_t = tanh(x_t@Wx + h_{t-1}@Wh + b)

#define BATCH 128
#define SEQ   1024
#define DIN   512
#define HID   512

// ---------------------------------------------------------------------------
// Kernel 1: xp[s][b][j] = sum_d x[b][s][d] * Wx[d][j] + bias[j]
// Tiled fp32 GEMM: M = steps*128 rows (r = s_local*128 + b), N=512, K=512.
// 64x64 tile, 256 threads, 4x4 microtile, K-step 16.
// ---------------------------------------------------------------------------
__global__ __launch_bounds__(256) void xp_gemm(
    const float* __restrict__ x, const float* __restrict__ Wx,
    const float* __restrict__ bias, float* __restrict__ xp,
    int s0)
{
    __shared__ __align__(16) float As[16][64 + 4];  // [kk][r], stride 68 (16B-aligned rows, no 2^5 stride)
    __shared__ __align__(16) float Bs[16][64];      // [kk][j]

    const int tid = threadIdx.x;            // 0..255
    const int tx = tid & 15;                // col group
    const int ty = tid >> 4;                // row group
    const int rowBase = blockIdx.x * 64;
    const int colBase = blockIdx.y * 64;

    // A-load mapping: r_local = tid>>2 (64 rows), k-chunk = (tid&3)*4 (float4)
    const int a_r  = tid >> 2;
    const int a_k4 = (tid & 3) * 4;
    const int rr   = rowBase + a_r;
    const int s    = s0 + (rr >> 7);        // s_local = rr/128
    const int bb   = rr & 127;
    const float* a_row = x + ((size_t)bb * SEQ + s) * DIN;

    // B-load mapping: kk = tid>>4, j-chunk = (tid&15)*4
    const int b_kk = tid >> 4;
    const int b_j4 = (tid & 15) * 4;

    float C[4][4] = {};

    for (int k0 = 0; k0 < DIN; k0 += 16) {
        // stage A tile (64 rows x 16 k)
        float4 av = *reinterpret_cast<const float4*>(a_row + k0 + a_k4);
        As[a_k4 + 0][a_r] = av.x;
        As[a_k4 + 1][a_r] = av.y;
        As[a_k4 + 2][a_r] = av.z;
        As[a_k4 + 3][a_r] = av.w;
        // stage B tile (16 k x 64 j)
        float4 bv = *reinterpret_cast<const float4*>(Wx + (size_t)(k0 + b_kk) * HID + colBase + b_j4);
        *reinterpret_cast<float4*>(&Bs[b_kk][b_j4]) = bv;
        __syncthreads();

        #pragma unroll
        for (int kk = 0; kk < 16; ++kk) {
            float4 a4 = *reinterpret_cast<const float4*>(&As[kk][ty * 4]);
            float4 b4 = *reinterpret_cast<const float4*>(&Bs[kk][tx * 4]);
            float a[4] = {a4.x, a4.y, a4.z, a4.w};
            float b[4] = {b4.x, b4.y, b4.z, b4.w};
            #pragma unroll
            for (int i = 0; i < 4; ++i)
                #pragma unroll
                for (int j = 0; j < 4; ++j)
                    C[i][j] += a[i] * b[j];
        }
        __syncthreads();
    }

    // epilogue: + bias, store float4
    float4 bias4 = *reinterpret_cast<const float4*>(bias + colBase + tx * 4);
    #pragma unroll
    for (int i = 0; i < 4; ++i) {
        int orow = rowBase + ty * 4 + i;
        float4 o;
        o.x = C[i][0] + bias4.x;
        o.y = C[i][1] + bias4.y;
        o.z = C[i][2] + bias4.z;
        o.w = C[i][3] + bias4.w;
        *reinterpret_cast<float4*>(xp + (size_t)orow * HID + colBase + tx * 4) = o;
    }
}

// ---------------------------------------------------------------------------
// Kernel 2: recurrence over `steps` timesteps. One block = 2 batch rows
// (shares each Wh load across 2 FMAs). 512 threads, thread j owns column j.
// h kept in LDS (broadcast reads). h persists in ws across chunk launches.
// ---------------------------------------------------------------------------
__global__ __launch_bounds__(512) void recur_kernel(
    const float* __restrict__ xp, const float* __restrict__ Wh,
    float* __restrict__ h_state, float* __restrict__ out,
    int steps, int init_h, int write_out)
{
    __shared__ __align__(16) float h0[HID];
    __shared__ __align__(16) float h1[HID];

    const int j = threadIdx.x;              // 0..511
    const int b0 = blockIdx.x * 2;
    const int b1 = b0 + 1;

    if (init_h) {
        h0[j] = 0.0f;
        h1[j] = 0.0f;
    } else {
        h0[j] = h_state[(size_t)b0 * HID + j];
        h1[j] = h_state[(size_t)b1 * HID + j];
    }
    __syncthreads();

    const float4* h04 = reinterpret_cast<const float4*>(h0);
    const float4* h14 = reinterpret_cast<const float4*>(h1);

    for (int s = 0; s < steps; ++s) {
        float acc0 = xp[(size_t)s * (BATCH * HID) + (size_t)b0 * HID + j];
        float acc1 = xp[(size_t)s * (BATCH * HID) + (size_t)b1 * HID + j];

        const float* w = Wh + j;
        #pragma unroll 2
        for (int k4 = 0; k4 < HID / 4; ++k4) {
            float4 hv0 = h04[k4];
            float4 hv1 = h14[k4];
            int k = k4 * 4;
            float w0 = w[(size_t)(k + 0) * HID];
            float w1 = w[(size_t)(k + 1) * HID];
            float w2 = w[(size_t)(k + 2) * HID];
            float w3 = w[(size_t)(k + 3) * HID];
            acc0 += hv0.x * w0;  acc1 += hv1.x * w0;
            acc0 += hv0.y * w1;  acc1 += hv1.y * w1;
            acc0 += hv0.z * w2;  acc1 += hv1.z * w2;
            acc0 += hv0.w * w3;  acc1 += hv1.w * w3;
        }

        float n0 = tanhf(acc0);
        float n1 = tanhf(acc1);
        __syncthreads();
        h0[j] = n0;
        h1[j] = n1;
        __syncthreads();
    }

    h_state[(size_t)b0 * HID + j] = h0[j];
    h_state[(size_t)b1 * HID + j] = h1[j];
    if (write_out) {
        out[(size_t)b0 * HID + j] = h0[j];
        out[(size_t)b1 * HID + j] = h1[j];
    }
}

// ---------------------------------------------------------------------------
// Fallback (only if ws too small to hold h + >=1 step of xp): fully fused,
// computes x@Wx inline each step. ~2x slower but needs zero workspace.
// ---------------------------------------------------------------------------
__global__ __launch_bounds__(512) void fused_kernel(
    const float* __restrict__ x, const float* __restrict__ Wx,
    const float* __restrict__ Wh, const float* __restrict__ bias,
    float* __restrict__ out)
{
    __shared__ __align__(16) float h0[HID];
    __shared__ __align__(16) float h1[HID];
    __shared__ __align__(16) float x0[DIN];
    __shared__ __align__(16) float x1[DIN];

    const int j = threadIdx.x;
    const int b0 = blockIdx.x * 2;
    const int b1 = b0 + 1;

    h0[j] = 0.0f;
    h1[j] = 0.0f;
    __syncthreads();

    const float4* h04 = reinterpret_cast<const float4*>(h0);
    const float4* h14 = reinterpret_cast<const float4*>(h1);
    const float4* x04 = reinterpret_cast<const float4*>(x0);
    const float4* x14 = reinterpret_cast<const float4*>(x1);

    for (int s = 0; s < SEQ; ++s) {
        x0[j] = x[((size_t)b0 * SEQ + s) * DIN + j];
        x1[j] = x[((size_t)b1 * SEQ + s) * DIN + j];
        __syncthreads();

        float acc0 = bias[j];
        float acc1 = bias[j];
        const float* wx = Wx + j;
        const float* wh = Wh + j;
        #pragma unroll 2
        for (int k4 = 0; k4 < HID / 4; ++k4) {
            float4 hv0 = h04[k4];
            float4 hv1 = h14[k4];
            float4 xv0 = x04[k4];
            float4 xv1 = x14[k4];
            int k = k4 * 4;
            #pragma unroll
            for (int u = 0; u < 4; ++u) {
                float wxv = wx[(size_t)(k + u) * HID];
                float whv = wh[(size_t)(k + u) * HID];
                float he0 = (u == 0) ? hv0.x : (u == 1) ? hv0.y : (u == 2) ? hv0.z : hv0.w;
                float he1 = (u == 0) ? hv1.x : (u == 1) ? hv1.y : (u == 2) ? hv1.z : hv1.w;
                float xe0 = (u == 0) ? xv0.x : (u == 1) ? xv0.y : (u == 2) ? xv0.z : xv0.w;
                float xe1 = (u == 0) ? xv1.x : (u == 1) ? xv1.y : (u == 2) ? xv1.z : xv1.w;
                acc0 += xe0 * wxv + he0 * whv;
                acc1 += xe1 * wxv + he1 * whv;
            }
        }

        float n0 = tanhf(acc0);
        float n1 = tanhf(acc1);
        __syncthreads();
        h0[j] = n0;
        h1[j] = n1;
        __syncthreads();
    }

    out[(size_t)b0 * HID + j] = h0[j];
    out[(size_t)b1 * HID + j] = h1[j];
}

// ---------------------------------------------------------------------------
extern "C" void kernel_launch(void* const* d_in, const int* in_sizes, int n_in,
                              void* d_out, int out_size, void* d_ws, size_t ws_size,
                              hipStream_t stream)
{
    const float* x    = (const float*)d_in[0];  // (128, 1024, 512)
    const float* Wx   = (const float*)d_in[1];  // (512, 512)
    const float* Wh   = (const float*)d_in[2];  // (512, 512)
    const float* bias = (const float*)d_in[3];  // (512,)
    float* out = (float*)d_out;                 // (128, 512)

    const size_t hBytes    = (size_t)BATCH * HID * sizeof(float);   // 256 KB
    const size_t stepBytes = (size_t)BATCH * HID * sizeof(float);   // 256 KB per timestep of xp

    size_t xpCapSteps = (ws_size > hBytes) ? (ws_size - hBytes) / stepBytes : 0;

    if (xpCapSteps >= 1) {
        int chunk = (int)((xpCapSteps < (size_t)SEQ) ? xpCapSteps : (size_t)SEQ);
        float* h_state = (float*)d_ws;
        float* xp = (float*)((char*)d_ws + hBytes);

        int s0 = 0;
        int first = 1;
        while (s0 < SEQ) {
            int steps = (SEQ - s0 < chunk) ? (SEQ - s0) : chunk;
            dim3 ggrid((unsigned)(steps * BATCH / 64), HID / 64);
            xp_gemm<<<ggrid, 256, 0, stream>>>(x, Wx, bias, xp, s0);
            int last = (s0 + steps >= SEQ) ? 1 : 0;
            recur_kernel<<<BATCH / 2, HID, 0, stream>>>(xp, Wh, h_state, out,
                                                        steps, first, last);
            first = 0;
            s0 += steps;
        }
    } else {
        fused_kernel<<<BATCH / 2, HID, 0, stream>>>(x, Wx, Wh, bias, out);
    }
}